// Round 5
// baseline (3362.522 us; speedup 1.0000x reference)
//
#include <hip/hip_runtime.h>
#include <hip/hip_cooperative_groups.h>

namespace cg = cooperative_groups;

// Peeling propagation on bipartite graph. V=1e6, F=4.2e6, K=3 (edge e -> function e/3).
// T=5. Output: deg (V floats) in d_out.
//
// R4 changes:
//  * k_pack_sort: no LDS staging (pass2 re-reads gpack, same-XCD L2-hot), 256-thr
//    blocks (SBLK=2048), shuffle-based scan, 1024-var bins. LDS 39.4 -> 8.2 KB.
//  * k_accum: wave-per-region coalesced segment bursts (was serial per-thread chains).
//  * k_iter: ONE cooperative kernel for zero-tmp + 5x(funcs, update) + out-decode,
//    with grid.sync + explicit __threadfence() (agent-scope wb/inv) at phase bounds.

static constexpr int Vn = 1000000;
static constexpr int Fn = 4200000;
static constexpr int Tn = 5;

static constexpr int SBLK = 2048;                          // sort blocks
static constexpr int FPB  = (Fn + SBLK - 1) / SBLK;        // 2051 functions/block
static constexpr int BIN_BITS = 10;                        // 1024 vars/bin
static constexpr int BIN_SIZE = 1 << BIN_BITS;
static constexpr int NB  = (Vn + BIN_SIZE - 1) >> BIN_BITS;   // 977 bins
static constexpr int NBP = 1024;                           // padded bin count (scan)
static constexpr int RCAP = 3 * FPB;                       // 6153 max entries/region
static constexpr int RSTRIDE = (RCAP + 63) & ~63;          // 6208 -> 128B-aligned regions
static constexpr int OROW = 1024;                          // offs row stride (u16)
static constexpr int AVW = (Vn + 1023) / 64;               // 15632 u64 mask words (bin-padded)

// ---- fused pack + histogram + shuffle-scan + block-private scatter ----
__global__ __launch_bounds__(256) void k_pack_sort(
    const int* __restrict__ vidx, const float* __restrict__ ef,
    const float* __restrict__ afunc,
    unsigned long long* __restrict__ gpack,
    unsigned short* __restrict__ offs,      // [SBLK][OROW] exclusive bin offsets
    unsigned short* __restrict__ sorted)    // [SBLK][RSTRIDE] block-private regions
{
    __shared__ unsigned int hist[NBP];
    __shared__ unsigned int cur[NBP];
    __shared__ unsigned int wsum[4];

    const int k = blockIdx.x;
    const int f0 = k * FPB;
    const int n = (Fn - f0 < FPB) ? (Fn - f0) : FPB;

    for (int i = threadIdx.x; i < NBP; i += 256) hist[i] = 0u;
    __syncthreads();

    // pass 1: read vidx/ef/afunc once, emit gpack, histogram bins
    for (int i = threadIdx.x; i < n; i += 256) {
        const int f = f0 + i, e0 = 3 * f;
        int v0 = vidx[e0], v1 = vidx[e0 + 1], v2 = vidx[e0 + 2];
        unsigned int s0 = ef[e0]     > 0.0f ? 1u : 0u;
        unsigned int s1 = ef[e0 + 1] > 0.0f ? 1u : 0u;
        unsigned int s2 = ef[e0 + 2] > 0.0f ? 1u : 0u;
        unsigned int act = afunc[f] != 0.0f ? 1u : 0u;
        unsigned long long g = (unsigned long long)(unsigned int)v0
                             | ((unsigned long long)(unsigned int)v1 << 20)
                             | ((unsigned long long)(unsigned int)v2 << 40)
                             | ((unsigned long long)s0 << 60)
                             | ((unsigned long long)s1 << 61)
                             | ((unsigned long long)s2 << 62)
                             | ((unsigned long long)act << 63);
        gpack[f] = g;
        if (act) {
            atomicAdd(&hist[v0 >> BIN_BITS], 1u);
            atomicAdd(&hist[v1 >> BIN_BITS], 1u);
            atomicAdd(&hist[v2 >> BIN_BITS], 1u);
        }
    }
    __syncthreads();

    // shuffle-based exclusive scan over 1024 bins (256 threads x 4 consecutive bins)
    {
        const int t = threadIdx.x, lane = t & 63, wid = t >> 6;
        unsigned int a0 = hist[4 * t], a1 = hist[4 * t + 1];
        unsigned int a2 = hist[4 * t + 2], a3 = hist[4 * t + 3];
        unsigned int tsum = a0 + a1 + a2 + a3;
        unsigned int x = tsum;
        #pragma unroll
        for (int off = 1; off < 64; off <<= 1) {
            unsigned int y = (unsigned int)__shfl_up((int)x, off);
            if (lane >= off) x += y;
        }
        if (lane == 63) wsum[wid] = x;
        __syncthreads();
        unsigned int wbase = 0;
        for (int w = 0; w < wid; ++w) wbase += wsum[w];
        unsigned int e0x = wbase + x - tsum;      // exclusive prefix of bin 4t
        unsigned int e1x = e0x + a0, e2x = e1x + a1, e3x = e2x + a2;
        cur[4 * t] = e0x; cur[4 * t + 1] = e1x; cur[4 * t + 2] = e2x; cur[4 * t + 3] = e3x;
        unsigned short* row = offs + (size_t)k * OROW;
        if (4 * t     <= NB) row[4 * t]     = (unsigned short)e0x;
        if (4 * t + 1 <= NB) row[4 * t + 1] = (unsigned short)e1x;
        if (4 * t + 2 <= NB) row[4 * t + 2] = (unsigned short)e2x;
        if (4 * t + 3 <= NB) row[4 * t + 3] = (unsigned short)e3x;
    }
    __syncthreads();

    // pass 2: re-read gpack (L2-hot, written by this block) and scatter
    const size_t rbase = (size_t)k * RSTRIDE;
    for (int i = threadIdx.x; i < n; i += 256) {
        unsigned long long g = gpack[f0 + i];
        if ((long long)g < 0) {
            unsigned int v0 = (unsigned int)(g & 0xFFFFFu);
            unsigned int v1 = (unsigned int)((g >> 20) & 0xFFFFFu);
            unsigned int v2 = (unsigned int)((g >> 40) & 0xFFFFFu);
            unsigned int sl0 = atomicAdd(&cur[v0 >> BIN_BITS], 1u);
            sorted[rbase + sl0] = (unsigned short)((v0 & (BIN_SIZE - 1)) | ((unsigned int)((g >> 60) & 1u) << BIN_BITS));
            unsigned int sl1 = atomicAdd(&cur[v1 >> BIN_BITS], 1u);
            sorted[rbase + sl1] = (unsigned short)((v1 & (BIN_SIZE - 1)) | ((unsigned int)((g >> 61) & 1u) << BIN_BITS));
            unsigned int sl2 = atomicAdd(&cur[v2 >> BIN_BITS], 1u);
            sorted[rbase + sl2] = (unsigned short)((v2 & (BIN_SIZE - 1)) | ((unsigned int)((g >> 62) & 1u) << BIN_BITS));
        }
    }
}

// ---- per-bin accumulate + decode. Wave-per-region: coalesced segment bursts. ----
__global__ __launch_bounds__(512) void k_accum(
    const unsigned short* __restrict__ offs,
    const unsigned short* __restrict__ sorted,
    const float* __restrict__ avars,
    unsigned int* __restrict__ packed,
    unsigned long long* __restrict__ avm,
    unsigned long long* __restrict__ svm)
{
    __shared__ unsigned int acc[BIN_SIZE];
    const int b = blockIdx.x;
    for (int i = threadIdx.x; i < BIN_SIZE; i += 512) acc[i] = 0u;
    __syncthreads();
    const int wid = threadIdx.x >> 6, lane = threadIdx.x & 63;
    for (int k = wid; k < SBLK; k += 8) {           // 256 regions per wave
        const int s0 = offs[(size_t)k * OROW + b];
        const int s1 = offs[(size_t)k * OROW + b + 1];
        const unsigned short* seg = sorted + (size_t)k * RSTRIDE;
        for (int e = s0 + lane; e < s1; e += 64) {  // one coalesced burst (avg 6 entries)
            unsigned int p = seg[e];
            atomicAdd(&acc[p & (BIN_SIZE - 1)], 0x10000u | (p >> BIN_BITS));
        }
    }
    __syncthreads();
    const int vbase = b << BIN_BITS;
    for (int i = threadIdx.x; i < BIN_SIZE; i += 512) {
        int v = vbase + i;
        bool valid = v < Vn;
        unsigned int p = valid ? acc[i] : 0u;
        bool av = valid && (avars[v] != 0.0f);
        unsigned int c = p >> 16, pos = p & 0xFFFFu;
        bool sv = av && (pos == 0u || pos == c);    // deg == |sdeg|
        unsigned long long avb = __ballot(av);
        unsigned long long svb = __ballot(sv);
        if (valid) packed[v] = p;
        if ((threadIdx.x & 63) == 0) {              // word index always < AVW (padded)
            avm[v >> 6] = avb;
            svm[v >> 6] = svb;
        }
    }
}

// ---- ONE cooperative kernel: zero tmp, 5 x (funcs-phase, update-phase), out. ----
__global__ __launch_bounds__(256) void k_iter(
    unsigned long long* __restrict__ gpack,
    unsigned int* __restrict__ packed,
    unsigned long long* __restrict__ avm,
    unsigned long long* __restrict__ svm,
    unsigned int* __restrict__ tmp,
    float* __restrict__ deg)
{
    cg::grid_group gg = cg::this_grid();
    const int gsz = gridDim.x * blockDim.x;         // 262144
    const int gid = blockIdx.x * blockDim.x + threadIdx.x;
    const int lane = threadIdx.x & 63;

    for (int v = gid; v < Vn; v += gsz) tmp[v] = 0u;
    __threadfence(); gg.sync(); __threadfence();

    for (int t = 0; t < Tn; ++t) {
        // function phase: stream gpack, gather single_v bitmask, sparse fire
        const unsigned int* s32 = (const unsigned int*)svm;
        for (int f = gid; f < Fn; f += gsz) {
            unsigned long long g = gpack[f];
            if ((long long)g >= 0) continue;        // inactive
            unsigned int v0 = (unsigned int)(g & 0xFFFFFu);
            unsigned int v1 = (unsigned int)((g >> 20) & 0xFFFFFu);
            unsigned int v2 = (unsigned int)((g >> 40) & 0xFFFFFu);
            unsigned int hit = ((s32[v0 >> 5] >> (v0 & 31u)) |
                                (s32[v1 >> 5] >> (v1 & 31u)) |
                                (s32[v2 >> 5] >> (v2 & 31u))) & 1u;
            if (!hit) continue;
            gpack[f] = g & ~(1ull << 63);           // deactivate (re-read only by this thread)
            atomicAdd(&tmp[v0], 0x10000u | (unsigned int)((g >> 60) & 1u));
            atomicAdd(&tmp[v1], 0x10000u | (unsigned int)((g >> 61) & 1u));
            atomicAdd(&tmp[v2], 0x10000u | (unsigned int)((g >> 62) & 1u));
        }
        __threadfence(); gg.sync(); __threadfence();

        // variable phase: packed -= tmp (av-gated); refresh av/sv bitmasks
        for (int v = gid; v < Vn; v += gsz) {
            unsigned long long avw = avm[v >> 6], svw = svm[v >> 6];
            bool av_old = (avw >> lane) & 1ull;
            bool sv     = (svw >> lane) & 1ull;
            bool av_new = av_old && !sv;
            unsigned int tp = tmp[v];
            unsigned int p = packed[v];
            if (tp != 0u) {
                if (av_old) { p -= tp; packed[v] = p; }
                tmp[v] = 0u;
            }
            unsigned int c = p >> 16, pos = p & 0xFFFFu;
            bool nsv = av_new && (pos == 0u || pos == c);
            unsigned long long nb = __ballot(nsv);
            if (lane == 0) {
                svm[v >> 6] = nb;
                avm[v >> 6] = avw & ~svw;
            }
        }
        __threadfence(); gg.sync(); __threadfence();
    }

    for (int v = gid; v < Vn; v += gsz) deg[v] = (float)(packed[v] >> 16);
}

extern "C" void kernel_launch(void* const* d_in, const int* in_sizes, int n_in,
                              void* d_out, int out_size, void* d_ws, size_t ws_size,
                              hipStream_t stream) {
    const int*   graph_map        = (const int*)d_in[0];   // row0 = vidx
    const float* edge_feature     = (const float*)d_in[1];
    const float* active_variables = (const float*)d_in[2];
    const float* active_functions = (const float*)d_in[3];
    const int* vidx = graph_map;

    float* deg = (float*)d_out;
    char* ws = (char*)d_ws;
    size_t off = 0;
    unsigned long long* gpack = (unsigned long long*)(ws + off); off += 8ull * Fn;             // 33.6 MB
    unsigned int* packed      = (unsigned int*)(ws + off);       off += 4ull * Vn;             // 4.0 MB
    unsigned long long* avm   = (unsigned long long*)(ws + off); off += 8ull * AVW;            // 125 KB
    unsigned long long* svm   = (unsigned long long*)(ws + off); off += 8ull * AVW;            // 125 KB
    unsigned short* offs      = (unsigned short*)(ws + off);     off += 2ull * SBLK * OROW;    // 4.2 MB
    unsigned short* sorted    = (unsigned short*)(ws + off);     off += 2ull * SBLK * RSTRIDE; // 25.4 MB
    unsigned int* tmp = (unsigned int*)sorted;   // alias: tmp (4 MB) reuses sorted after k_accum
    // total ~67.5 MB

    k_pack_sort<<<SBLK, 256, 0, stream>>>(vidx, edge_feature, active_functions, gpack, offs, sorted);
    k_accum<<<NB, 512, 0, stream>>>(offs, sorted, active_variables, packed, avm, svm);

    void* args[] = {(void*)&gpack, (void*)&packed, (void*)&avm, (void*)&svm, (void*)&tmp, (void*)&deg};
    hipLaunchCooperativeKernel((void*)k_iter, dim3(1024), dim3(256), args, 0, stream);
}

// Round 6
// 674.426 us; speedup vs baseline: 4.9858x; 4.9858x over previous
//
#include <hip/hip_runtime.h>

// Peeling propagation on bipartite graph. V=1e6, F=4.2e6, K=3 (edge e -> function e/3).
// T=5. Output: deg (V floats) in d_out.
//
// R5 post-mortem: fused cooperative k_iter regressed 10x — per-wave device-scope
// __threadfence() (L2 wb+inv, required by non-coherent per-XCD L2s) thrashed the
// cache-resident working set; 41 GB/s pure-latency execution. REVERTED to separate
// kernel launches (kernel-boundary coherence is ~free). Kept R4's improved
// k_pack_sort (256-thr, shuffle scan, no LDS staging) and k_accum (wave-per-region).

static constexpr int Vn = 1000000;
static constexpr int Fn = 4200000;
static constexpr int Tn = 5;

static constexpr int SBLK = 2048;                          // sort blocks
static constexpr int FPB  = (Fn + SBLK - 1) / SBLK;        // 2051 functions/block
static constexpr int BIN_BITS = 10;                        // 1024 vars/bin
static constexpr int BIN_SIZE = 1 << BIN_BITS;
static constexpr int NB  = (Vn + BIN_SIZE - 1) >> BIN_BITS;   // 977 bins
static constexpr int NBP = 1024;                           // padded bin count (scan)
static constexpr int RCAP = 3 * FPB;                       // 6153 max entries/region
static constexpr int RSTRIDE = (RCAP + 63) & ~63;          // 6208 -> 128B-aligned regions
static constexpr int OROW = 1024;                          // offs row stride (u16)
static constexpr int AVW = (Vn + 1023) / 64;               // 15632 u64 mask words (bin-padded)

// ---- fused pack + histogram + shuffle-scan + block-private scatter ----
__global__ __launch_bounds__(256) void k_pack_sort(
    const int* __restrict__ vidx, const float* __restrict__ ef,
    const float* __restrict__ afunc,
    unsigned long long* __restrict__ gpack,
    unsigned short* __restrict__ offs,      // [SBLK][OROW] exclusive bin offsets
    unsigned short* __restrict__ sorted)    // [SBLK][RSTRIDE] block-private regions
{
    __shared__ unsigned int hist[NBP];
    __shared__ unsigned int cur[NBP];
    __shared__ unsigned int wsum[4];

    const int k = blockIdx.x;
    const int f0 = k * FPB;
    const int n = (Fn - f0 < FPB) ? (Fn - f0) : FPB;

    for (int i = threadIdx.x; i < NBP; i += 256) hist[i] = 0u;
    __syncthreads();

    // pass 1: read vidx/ef/afunc once, emit gpack, histogram bins
    for (int i = threadIdx.x; i < n; i += 256) {
        const int f = f0 + i, e0 = 3 * f;
        int v0 = vidx[e0], v1 = vidx[e0 + 1], v2 = vidx[e0 + 2];
        unsigned int s0 = ef[e0]     > 0.0f ? 1u : 0u;
        unsigned int s1 = ef[e0 + 1] > 0.0f ? 1u : 0u;
        unsigned int s2 = ef[e0 + 2] > 0.0f ? 1u : 0u;
        unsigned int act = afunc[f] != 0.0f ? 1u : 0u;
        unsigned long long g = (unsigned long long)(unsigned int)v0
                             | ((unsigned long long)(unsigned int)v1 << 20)
                             | ((unsigned long long)(unsigned int)v2 << 40)
                             | ((unsigned long long)s0 << 60)
                             | ((unsigned long long)s1 << 61)
                             | ((unsigned long long)s2 << 62)
                             | ((unsigned long long)act << 63);
        gpack[f] = g;
        if (act) {
            atomicAdd(&hist[v0 >> BIN_BITS], 1u);
            atomicAdd(&hist[v1 >> BIN_BITS], 1u);
            atomicAdd(&hist[v2 >> BIN_BITS], 1u);
        }
    }
    __syncthreads();

    // shuffle-based exclusive scan over 1024 bins (256 threads x 4 consecutive bins)
    {
        const int t = threadIdx.x, lane = t & 63, wid = t >> 6;
        unsigned int a0 = hist[4 * t], a1 = hist[4 * t + 1];
        unsigned int a2 = hist[4 * t + 2], a3 = hist[4 * t + 3];
        unsigned int tsum = a0 + a1 + a2 + a3;
        unsigned int x = tsum;
        #pragma unroll
        for (int off = 1; off < 64; off <<= 1) {
            unsigned int y = (unsigned int)__shfl_up((int)x, off);
            if (lane >= off) x += y;
        }
        if (lane == 63) wsum[wid] = x;
        __syncthreads();
        unsigned int wbase = 0;
        for (int w = 0; w < wid; ++w) wbase += wsum[w];
        unsigned int e0x = wbase + x - tsum;      // exclusive prefix of bin 4t
        unsigned int e1x = e0x + a0, e2x = e1x + a1, e3x = e2x + a2;
        cur[4 * t] = e0x; cur[4 * t + 1] = e1x; cur[4 * t + 2] = e2x; cur[4 * t + 3] = e3x;
        unsigned short* row = offs + (size_t)k * OROW;
        if (4 * t     <= NB) row[4 * t]     = (unsigned short)e0x;
        if (4 * t + 1 <= NB) row[4 * t + 1] = (unsigned short)e1x;
        if (4 * t + 2 <= NB) row[4 * t + 2] = (unsigned short)e2x;
        if (4 * t + 3 <= NB) row[4 * t + 3] = (unsigned short)e3x;
    }
    __syncthreads();

    // pass 2: re-read gpack (L2-hot, written by this block) and scatter
    const size_t rbase = (size_t)k * RSTRIDE;
    for (int i = threadIdx.x; i < n; i += 256) {
        unsigned long long g = gpack[f0 + i];
        if ((long long)g < 0) {
            unsigned int v0 = (unsigned int)(g & 0xFFFFFu);
            unsigned int v1 = (unsigned int)((g >> 20) & 0xFFFFFu);
            unsigned int v2 = (unsigned int)((g >> 40) & 0xFFFFFu);
            unsigned int sl0 = atomicAdd(&cur[v0 >> BIN_BITS], 1u);
            sorted[rbase + sl0] = (unsigned short)((v0 & (BIN_SIZE - 1)) | ((unsigned int)((g >> 60) & 1u) << BIN_BITS));
            unsigned int sl1 = atomicAdd(&cur[v1 >> BIN_BITS], 1u);
            sorted[rbase + sl1] = (unsigned short)((v1 & (BIN_SIZE - 1)) | ((unsigned int)((g >> 61) & 1u) << BIN_BITS));
            unsigned int sl2 = atomicAdd(&cur[v2 >> BIN_BITS], 1u);
            sorted[rbase + sl2] = (unsigned short)((v2 & (BIN_SIZE - 1)) | ((unsigned int)((g >> 62) & 1u) << BIN_BITS));
        }
    }
}

// ---- per-bin accumulate + decode. Wave-per-region: coalesced segment bursts. ----
__global__ __launch_bounds__(512) void k_accum(
    const unsigned short* __restrict__ offs,
    const unsigned short* __restrict__ sorted,
    const float* __restrict__ avars,
    unsigned int* __restrict__ packed,
    unsigned long long* __restrict__ avm,
    unsigned long long* __restrict__ svm)
{
    __shared__ unsigned int acc[BIN_SIZE];
    const int b = blockIdx.x;
    for (int i = threadIdx.x; i < BIN_SIZE; i += 512) acc[i] = 0u;
    __syncthreads();
    const int wid = threadIdx.x >> 6, lane = threadIdx.x & 63;
    for (int k = wid; k < SBLK; k += 8) {           // 256 regions per wave
        const int s0 = offs[(size_t)k * OROW + b];
        const int s1 = offs[(size_t)k * OROW + b + 1];
        const unsigned short* seg = sorted + (size_t)k * RSTRIDE;
        for (int e = s0 + lane; e < s1; e += 64) {  // one coalesced burst (avg 6 entries)
            unsigned int p = seg[e];
            atomicAdd(&acc[p & (BIN_SIZE - 1)], 0x10000u | (p >> BIN_BITS));
        }
    }
    __syncthreads();
    const int vbase = b << BIN_BITS;
    for (int i = threadIdx.x; i < BIN_SIZE; i += 512) {
        int v = vbase + i;
        bool valid = v < Vn;
        unsigned int p = valid ? acc[i] : 0u;
        bool av = valid && (avars[v] != 0.0f);
        unsigned int c = p >> 16, pos = p & 0xFFFFu;
        bool sv = av && (pos == 0u || pos == c);    // deg == |sdeg|
        unsigned long long avb = __ballot(av);
        unsigned long long svb = __ballot(sv);
        if (valid) packed[v] = p;
        if ((threadIdx.x & 63) == 0) {              // word index always < AVW (padded)
            avm[v >> 6] = avb;
            svm[v >> 6] = svb;
        }
    }
}

__global__ void k_zero_tmp(unsigned int* __restrict__ tmp) {
    int v = blockIdx.x * blockDim.x + threadIdx.x;
    if (v < Vn) tmp[v] = 0u;
}

// ---- iteration: function side. gpack stream + 3 bitmask gathers; sparse fire. ----
__global__ void k_funcs(unsigned long long* __restrict__ gpack,
                        const unsigned int* __restrict__ svm32,
                        unsigned int* __restrict__ tmp)
{
    int f = blockIdx.x * blockDim.x + threadIdx.x;
    if (f >= Fn) return;
    unsigned long long g = gpack[f];
    if ((long long)g >= 0) return;               // inactive (bit63 clear)
    unsigned int v0 = (unsigned int)(g & 0xFFFFFu);
    unsigned int v1 = (unsigned int)((g >> 20) & 0xFFFFFu);
    unsigned int v2 = (unsigned int)((g >> 40) & 0xFFFFFu);
    unsigned int hit = ((svm32[v0 >> 5] >> (v0 & 31u)) |
                        (svm32[v1 >> 5] >> (v1 & 31u)) |
                        (svm32[v2 >> 5] >> (v2 & 31u))) & 1u;
    if (!hit) return;
    gpack[f] = g & ~(1ull << 63);                // function deactivates (single_f = 1)
    atomicAdd(&tmp[v0], 0x10000u | (unsigned int)((g >> 60) & 1u));
    atomicAdd(&tmp[v1], 0x10000u | (unsigned int)((g >> 61) & 1u));
    atomicAdd(&tmp[v2], 0x10000u | (unsigned int)((g >> 62) & 1u));
}

// ---- iteration: variable side. packed -= tmp (av-gated), refresh av/sv bitmasks. ----
__global__ void k_update(unsigned int* __restrict__ packed,
                         unsigned int* __restrict__ tmp,
                         unsigned long long* __restrict__ avm,
                         unsigned long long* __restrict__ svm)
{
    int v = blockIdx.x * blockDim.x + threadIdx.x;
    int lane = threadIdx.x & 63;
    bool valid = v < Vn;
    unsigned long long avw = 0ull, svw = 0ull;
    if (valid) { avw = avm[v >> 6]; svw = svm[v >> 6]; }   // wave-broadcast loads
    bool av_old = valid && ((avw >> lane) & 1ull);
    bool sv     = valid && ((svw >> lane) & 1ull);
    bool av_new = av_old && !sv;                            // av *= (1 - single_v)
    unsigned int p = 0u;
    if (valid) {
        unsigned int tp = tmp[v];
        p = packed[v];
        if (tp != 0u) {
            if (av_old) { p -= tp; packed[v] = p; }         // deg -= seg*av (field-safe)
            tmp[v] = 0u;
        }
    }
    unsigned int c = p >> 16, pos = p & 0xFFFFu;
    bool nsv = av_new && (pos == 0u || pos == c);           // next single_v
    unsigned long long nsvb = __ballot(nsv);
    if (lane == 0 && valid) {
        svm[v >> 6] = nsvb;
        avm[v >> 6] = avw & ~svw;
    }
}

__global__ void k_out(const unsigned int* __restrict__ packed, float* __restrict__ deg) {
    int v = blockIdx.x * blockDim.x + threadIdx.x;
    if (v < Vn) deg[v] = (float)(packed[v] >> 16);
}

extern "C" void kernel_launch(void* const* d_in, const int* in_sizes, int n_in,
                              void* d_out, int out_size, void* d_ws, size_t ws_size,
                              hipStream_t stream) {
    const int*   graph_map        = (const int*)d_in[0];   // row0 = vidx
    const float* edge_feature     = (const float*)d_in[1];
    const float* active_variables = (const float*)d_in[2];
    const float* active_functions = (const float*)d_in[3];
    const int* vidx = graph_map;

    float* deg = (float*)d_out;
    char* ws = (char*)d_ws;
    size_t off = 0;
    unsigned long long* gpack = (unsigned long long*)(ws + off); off += 8ull * Fn;             // 33.6 MB
    unsigned int* packed      = (unsigned int*)(ws + off);       off += 4ull * Vn;             // 4.0 MB
    unsigned long long* avm   = (unsigned long long*)(ws + off); off += 8ull * AVW;            // 125 KB
    unsigned long long* svm   = (unsigned long long*)(ws + off); off += 8ull * AVW;            // 125 KB
    unsigned short* offs      = (unsigned short*)(ws + off);     off += 2ull * SBLK * OROW;    // 4.2 MB
    unsigned short* sorted    = (unsigned short*)(ws + off);     off += 2ull * SBLK * RSTRIDE; // 25.4 MB
    unsigned int* tmp = (unsigned int*)sorted;   // alias: tmp (4 MB) reuses sorted after k_accum
    // total ~67.5 MB

    const int BS = 256;
    const int gV = (Vn + BS - 1) / BS;
    const int gF = (Fn + BS - 1) / BS;

    k_pack_sort<<<SBLK, 256, 0, stream>>>(vidx, edge_feature, active_functions, gpack, offs, sorted);
    k_accum<<<NB, 512, 0, stream>>>(offs, sorted, active_variables, packed, avm, svm);
    k_zero_tmp<<<gV, BS, 0, stream>>>(tmp);
    for (int t = 0; t < Tn; ++t) {
        k_funcs<<<gF, BS, 0, stream>>>(gpack, (const unsigned int*)svm, tmp);
        k_update<<<gV, BS, 0, stream>>>(packed, tmp, avm, svm);
    }
    k_out<<<gV, BS, 0, stream>>>(packed, deg);
}

// Round 7
// 563.867 us; speedup vs baseline: 5.9633x; 1.1961x over previous
//
#include <hip/hip_runtime.h>

// Peeling propagation on bipartite graph. V=1e6, F=4.2e6, K=3 (edge e -> function e/3).
// T=5. Output: deg (V floats) in d_out.
//
// R6 post-mortem: wave-per-region k_accum regressed 2.4x (6-entry segments -> 58/64
// lanes idle + serial dependent offs/seg chains + full-line pulls for 12B reads).
// R7: entries now encode 12-bit chunk-local v (chunk = 4 fine bins = 4096 vars), so
// accum reads ONE contiguous ~49B span per (region,chunk): [offs[4c], offs[4c+4]).
// offs is transposed (tiled kernel) so bounds staging is contiguous. Accum is
// thread-per-region, 245 blocks x 1024 thr, bounds in LDS. pack_sort structure
// (1024 fine-bin hist/scan/scatter) unchanged. k_out folded into last k_update.

static constexpr int Vn = 1000000;
static constexpr int Fn = 4200000;
static constexpr int Tn = 5;

static constexpr int SBLK = 2048;                          // sort blocks / regions
static constexpr int FPB  = (Fn + SBLK - 1) / SBLK;        // 2051 functions/block
static constexpr int BIN_BITS = 10;                        // fine bin = 1024 vars (sort granularity)
static constexpr int BIN_SIZE = 1 << BIN_BITS;
static constexpr int NB  = (Vn + BIN_SIZE - 1) >> BIN_BITS;   // 977 fine bins
static constexpr int NBP = 1024;                           // padded fine-bin count (scan)
static constexpr int CH_BITS = 12;                         // chunk = 4096 vars (accum granularity)
static constexpr int CH_SIZE = 1 << CH_BITS;
static constexpr int NCH = (Vn + CH_SIZE - 1) >> CH_BITS;  // 245 chunks
static constexpr int RCAP = 3 * FPB;                       // 6153 max entries/region
static constexpr int RSTRIDE = (RCAP + 63) & ~63;          // 6208 -> 128B-aligned regions
static constexpr int OROW = 1024;                          // offs row stride (u16)
static constexpr int AVW = NCH * (CH_SIZE / 64);           // 15680 u64 mask words (chunk-padded)

// ---- fused pack + histogram + shuffle-scan + block-private scatter ----
__global__ __launch_bounds__(256) void k_pack_sort(
    const int* __restrict__ vidx, const float* __restrict__ ef,
    const float* __restrict__ afunc,
    unsigned long long* __restrict__ gpack,
    unsigned short* __restrict__ offs,      // [SBLK][OROW] exclusive fine-bin offsets
    unsigned short* __restrict__ sorted)    // [SBLK][RSTRIDE] block-private regions
{
    __shared__ unsigned int hist[NBP];
    __shared__ unsigned int cur[NBP];
    __shared__ unsigned int wsum[4];

    const int k = blockIdx.x;
    const int f0 = k * FPB;
    const int n = (Fn - f0 < FPB) ? (Fn - f0) : FPB;

    for (int i = threadIdx.x; i < NBP; i += 256) hist[i] = 0u;
    __syncthreads();

    // pass 1: read vidx/ef/afunc once, emit gpack, histogram fine bins
    for (int i = threadIdx.x; i < n; i += 256) {
        const int f = f0 + i, e0 = 3 * f;
        int v0 = vidx[e0], v1 = vidx[e0 + 1], v2 = vidx[e0 + 2];
        unsigned int s0 = ef[e0]     > 0.0f ? 1u : 0u;
        unsigned int s1 = ef[e0 + 1] > 0.0f ? 1u : 0u;
        unsigned int s2 = ef[e0 + 2] > 0.0f ? 1u : 0u;
        unsigned int act = afunc[f] != 0.0f ? 1u : 0u;
        unsigned long long g = (unsigned long long)(unsigned int)v0
                             | ((unsigned long long)(unsigned int)v1 << 20)
                             | ((unsigned long long)(unsigned int)v2 << 40)
                             | ((unsigned long long)s0 << 60)
                             | ((unsigned long long)s1 << 61)
                             | ((unsigned long long)s2 << 62)
                             | ((unsigned long long)act << 63);
        gpack[f] = g;
        if (act) {
            atomicAdd(&hist[v0 >> BIN_BITS], 1u);
            atomicAdd(&hist[v1 >> BIN_BITS], 1u);
            atomicAdd(&hist[v2 >> BIN_BITS], 1u);
        }
    }
    __syncthreads();

    // shuffle-based exclusive scan over 1024 fine bins (256 threads x 4 bins)
    {
        const int t = threadIdx.x, lane = t & 63, wid = t >> 6;
        unsigned int a0 = hist[4 * t], a1 = hist[4 * t + 1];
        unsigned int a2 = hist[4 * t + 2], a3 = hist[4 * t + 3];
        unsigned int tsum = a0 + a1 + a2 + a3;
        unsigned int x = tsum;
        #pragma unroll
        for (int off = 1; off < 64; off <<= 1) {
            unsigned int y = (unsigned int)__shfl_up((int)x, off);
            if (lane >= off) x += y;
        }
        if (lane == 63) wsum[wid] = x;
        __syncthreads();
        unsigned int wbase = 0;
        for (int w = 0; w < wid; ++w) wbase += wsum[w];
        unsigned int e0x = wbase + x - tsum;      // exclusive prefix of bin 4t
        unsigned int e1x = e0x + a0, e2x = e1x + a1, e3x = e2x + a2;
        cur[4 * t] = e0x; cur[4 * t + 1] = e1x; cur[4 * t + 2] = e2x; cur[4 * t + 3] = e3x;
        unsigned short* row = offs + (size_t)k * OROW;
        if (4 * t     <= NB) row[4 * t]     = (unsigned short)e0x;
        if (4 * t + 1 <= NB) row[4 * t + 1] = (unsigned short)e1x;
        if (4 * t + 2 <= NB) row[4 * t + 2] = (unsigned short)e2x;
        if (4 * t + 3 <= NB) row[4 * t + 3] = (unsigned short)e3x;
    }
    __syncthreads();

    // pass 2: re-read gpack (L2-hot) and scatter; entry = 12-bit chunk-local v | sign<<12
    const size_t rbase = (size_t)k * RSTRIDE;
    for (int i = threadIdx.x; i < n; i += 256) {
        unsigned long long g = gpack[f0 + i];
        if ((long long)g < 0) {
            unsigned int v0 = (unsigned int)(g & 0xFFFFFu);
            unsigned int v1 = (unsigned int)((g >> 20) & 0xFFFFFu);
            unsigned int v2 = (unsigned int)((g >> 40) & 0xFFFFFu);
            unsigned int sl0 = atomicAdd(&cur[v0 >> BIN_BITS], 1u);
            sorted[rbase + sl0] = (unsigned short)((v0 & (CH_SIZE - 1)) | ((unsigned int)((g >> 60) & 1u) << CH_BITS));
            unsigned int sl1 = atomicAdd(&cur[v1 >> BIN_BITS], 1u);
            sorted[rbase + sl1] = (unsigned short)((v1 & (CH_SIZE - 1)) | ((unsigned int)((g >> 61) & 1u) << CH_BITS));
            unsigned int sl2 = atomicAdd(&cur[v2 >> BIN_BITS], 1u);
            sorted[rbase + sl2] = (unsigned short)((v2 & (CH_SIZE - 1)) | ((unsigned int)((g >> 62) & 1u) << CH_BITS));
        }
    }
}

// ---- tiled transpose: offs [SBLK][1024] -> offs_T [1024][SBLK] ----
__global__ __launch_bounds__(256) void k_transpose(const unsigned short* __restrict__ in,
                                                   unsigned short* __restrict__ out) {
    __shared__ unsigned short t[64][65];
    const int bx = blockIdx.x;   // 16 col tiles (1024/64)
    const int by = blockIdx.y;   // 32 row tiles (2048/64)
    for (int i = threadIdx.x; i < 64 * 64; i += 256) {
        int r = i >> 6, c = i & 63;
        t[r][c] = in[(size_t)(by * 64 + r) * OROW + (bx * 64 + c)];
    }
    __syncthreads();
    for (int i = threadIdx.x; i < 64 * 64; i += 256) {
        int r = i >> 6, c = i & 63;
        out[(size_t)(bx * 64 + r) * SBLK + (by * 64 + c)] = t[c][r];
    }
}

// ---- per-chunk accumulate + decode. Thread-per-region, contiguous ~49B spans. ----
__global__ __launch_bounds__(1024) void k_accum(
    const unsigned short* __restrict__ offs_T,   // [1024][SBLK]
    const unsigned short* __restrict__ sorted,
    const float* __restrict__ avars,
    unsigned int* __restrict__ packed,
    unsigned long long* __restrict__ avm,
    unsigned long long* __restrict__ svm)
{
    __shared__ unsigned int acc[CH_SIZE];        // 16 KB
    __shared__ unsigned short row0[SBLK];        // 4 KB
    __shared__ unsigned short row1[SBLK];        // 4 KB
    const int c = blockIdx.x;                    // chunk 0..244
    const int r0 = 4 * c;
    const int r1 = (4 * c + 4 < NB) ? (4 * c + 4) : NB;
    for (int i = threadIdx.x; i < CH_SIZE; i += 1024) acc[i] = 0u;
    for (int i = threadIdx.x; i < SBLK; i += 1024) {
        row0[i] = offs_T[(size_t)r0 * SBLK + i];
        row1[i] = offs_T[(size_t)r1 * SBLK + i];
    }
    __syncthreads();
    for (int k = threadIdx.x; k < SBLK; k += 1024) {   // 2 regions per thread
        const int s0 = row0[k], s1 = row1[k];
        const unsigned short* seg = sorted + (size_t)k * RSTRIDE;
        for (int e = s0; e < s1; ++e) {                // ~25 contiguous u16 loads, independent
            unsigned int p = seg[e];
            atomicAdd(&acc[p & (CH_SIZE - 1)], 0x10000u | (p >> CH_BITS));
        }
    }
    __syncthreads();
    const int vbase = c << CH_BITS;
    for (int i = threadIdx.x; i < CH_SIZE; i += 1024) {
        int v = vbase + i;
        bool valid = v < Vn;
        unsigned int p = valid ? acc[i] : 0u;
        bool av = valid && (avars[v] != 0.0f);
        unsigned int cnt = p >> 16, pos = p & 0xFFFFu;
        bool sv = av && (pos == 0u || pos == cnt);    // deg == |sdeg|
        unsigned long long avb = __ballot(av);
        unsigned long long svb = __ballot(sv);
        if (valid) packed[v] = p;
        if ((threadIdx.x & 63) == 0) {                // word index < AVW (chunk-padded)
            avm[v >> 6] = avb;
            svm[v >> 6] = svb;
        }
    }
}

__global__ void k_zero_tmp(unsigned int* __restrict__ tmp) {
    int v = blockIdx.x * blockDim.x + threadIdx.x;
    if (v < Vn) tmp[v] = 0u;
}

// ---- iteration: function side. gpack stream + 3 bitmask gathers; sparse fire. ----
__global__ void k_funcs(unsigned long long* __restrict__ gpack,
                        const unsigned int* __restrict__ svm32,
                        unsigned int* __restrict__ tmp)
{
    int f = blockIdx.x * blockDim.x + threadIdx.x;
    if (f >= Fn) return;
    unsigned long long g = gpack[f];
    if ((long long)g >= 0) return;               // inactive (bit63 clear)
    unsigned int v0 = (unsigned int)(g & 0xFFFFFu);
    unsigned int v1 = (unsigned int)((g >> 20) & 0xFFFFFu);
    unsigned int v2 = (unsigned int)((g >> 40) & 0xFFFFFu);
    unsigned int hit = ((svm32[v0 >> 5] >> (v0 & 31u)) |
                        (svm32[v1 >> 5] >> (v1 & 31u)) |
                        (svm32[v2 >> 5] >> (v2 & 31u))) & 1u;
    if (!hit) return;
    gpack[f] = g & ~(1ull << 63);                // function deactivates (single_f = 1)
    atomicAdd(&tmp[v0], 0x10000u | (unsigned int)((g >> 60) & 1u));
    atomicAdd(&tmp[v1], 0x10000u | (unsigned int)((g >> 61) & 1u));
    atomicAdd(&tmp[v2], 0x10000u | (unsigned int)((g >> 62) & 1u));
}

// ---- iteration: variable side. packed -= tmp (av-gated), refresh av/sv bitmasks.
//      write_deg!=0 on the last iteration: also decode deg to float (folds k_out). ----
__global__ void k_update(unsigned int* __restrict__ packed,
                         unsigned int* __restrict__ tmp,
                         unsigned long long* __restrict__ avm,
                         unsigned long long* __restrict__ svm,
                         float* __restrict__ deg, int write_deg)
{
    int v = blockIdx.x * blockDim.x + threadIdx.x;
    int lane = threadIdx.x & 63;
    bool valid = v < Vn;
    unsigned long long avw = 0ull, svw = 0ull;
    if (valid) { avw = avm[v >> 6]; svw = svm[v >> 6]; }   // wave-broadcast loads
    bool av_old = valid && ((avw >> lane) & 1ull);
    bool sv     = valid && ((svw >> lane) & 1ull);
    bool av_new = av_old && !sv;                            // av *= (1 - single_v)
    unsigned int p = 0u;
    if (valid) {
        unsigned int tp = tmp[v];
        p = packed[v];
        if (tp != 0u) {
            if (av_old) { p -= tp; packed[v] = p; }         // deg -= seg*av (field-safe)
            tmp[v] = 0u;
        }
    }
    unsigned int c = p >> 16, pos = p & 0xFFFFu;
    bool nsv = av_new && (pos == 0u || pos == c);           // next single_v
    unsigned long long nsvb = __ballot(nsv);
    if (lane == 0 && valid) {
        svm[v >> 6] = nsvb;
        avm[v >> 6] = avw & ~svw;
    }
    if (write_deg && valid) deg[v] = (float)c;
}

extern "C" void kernel_launch(void* const* d_in, const int* in_sizes, int n_in,
                              void* d_out, int out_size, void* d_ws, size_t ws_size,
                              hipStream_t stream) {
    const int*   graph_map        = (const int*)d_in[0];   // row0 = vidx
    const float* edge_feature     = (const float*)d_in[1];
    const float* active_variables = (const float*)d_in[2];
    const float* active_functions = (const float*)d_in[3];
    const int* vidx = graph_map;

    float* deg = (float*)d_out;
    char* ws = (char*)d_ws;
    size_t off = 0;
    unsigned long long* gpack = (unsigned long long*)(ws + off); off += 8ull * Fn;             // 33.6 MB
    unsigned int* packed      = (unsigned int*)(ws + off);       off += 4ull * Vn;             // 4.0 MB
    unsigned long long* avm   = (unsigned long long*)(ws + off); off += 8ull * AVW;            // 125 KB
    unsigned long long* svm   = (unsigned long long*)(ws + off); off += 8ull * AVW;            // 125 KB
    unsigned short* offs      = (unsigned short*)(ws + off);     off += 2ull * SBLK * OROW;    // 4.2 MB
    unsigned short* offs_T    = (unsigned short*)(ws + off);     off += 2ull * SBLK * OROW;    // 4.2 MB
    unsigned short* sorted    = (unsigned short*)(ws + off);     off += 2ull * SBLK * RSTRIDE; // 25.4 MB
    unsigned int* tmp = (unsigned int*)sorted;   // alias: tmp (4 MB) reuses sorted after k_accum
    // total ~71.7 MB

    const int BS = 256;
    const int gV = (Vn + BS - 1) / BS;
    const int gF = (Fn + BS - 1) / BS;

    k_pack_sort<<<SBLK, 256, 0, stream>>>(vidx, edge_feature, active_functions, gpack, offs, sorted);
    k_transpose<<<dim3(OROW / 64, SBLK / 64), 256, 0, stream>>>(offs, offs_T);
    k_accum<<<NCH, 1024, 0, stream>>>(offs_T, sorted, active_variables, packed, avm, svm);
    k_zero_tmp<<<gV, BS, 0, stream>>>(tmp);
    for (int t = 0; t < Tn; ++t) {
        k_funcs<<<gF, BS, 0, stream>>>(gpack, (const unsigned int*)svm, tmp);
        k_update<<<gV, BS, 0, stream>>>(packed, tmp, avm, svm, deg, (t == Tn - 1) ? 1 : 0);
    }
}

// Round 8
// 463.411 us; speedup vs baseline: 7.2560x; 1.2168x over previous
//
#include <hip/hip_runtime.h>

// Peeling propagation on bipartite graph. V=1e6, F=4.2e6, K=3 (edge e -> function e/3).
// T=5. Output: deg (V floats) in d_out.
//
// R8 changes (R7 had ~355us in the iteration path: 12.6M random L2 bitmask probes/iter):
//  * k_funcs: L1-resident group filter (s_grp[w]=any single in 64-var word, 15.7KB byte
//    array) probed BEFORE the fine L2 bitmask; 2 fns/thread via ulonglong2 gpack loads.
//  * k_update: tmp_grp byte array gates the 4MB tmp read (skip clean 64-var words).
//  * k_pack_sort: FPB 2051->2052 aligns edge bases to 16B -> int4/float4/ulonglong2
//    vectorized passes (4 fns/thread-iter).

static constexpr int Vn = 1000000;
static constexpr int Fn = 4200000;
static constexpr int Tn = 5;

static constexpr int SBLK = 2048;                          // sort blocks / regions
static constexpr int FPB  = 2052;                          // functions/block (mult of 4 for int4 alignment)
static constexpr int BIN_BITS = 10;                        // fine bin = 1024 vars (sort granularity)
static constexpr int BIN_SIZE = 1 << BIN_BITS;
static constexpr int NB  = (Vn + BIN_SIZE - 1) >> BIN_BITS;   // 977 fine bins
static constexpr int NBP = 1024;                           // padded fine-bin count (scan)
static constexpr int CH_BITS = 12;                         // chunk = 4096 vars (accum granularity)
static constexpr int CH_SIZE = 1 << CH_BITS;
static constexpr int NCH = (Vn + CH_SIZE - 1) >> CH_BITS;  // 245 chunks
static constexpr int RCAP = 3 * FPB;                       // 6156 max entries/region
static constexpr int RSTRIDE = (RCAP + 63) & ~63;          // 6208 -> 128B-aligned regions
static constexpr int OROW = 1024;                          // offs row stride (u16)
static constexpr int AVW = NCH * (CH_SIZE / 64);           // 15680 u64 mask words (chunk-padded)

// ---- fused pack + histogram + shuffle-scan + block-private scatter ----
__global__ __launch_bounds__(256) void k_pack_sort(
    const int* __restrict__ vidx, const float* __restrict__ ef,
    const float* __restrict__ afunc,
    unsigned long long* __restrict__ gpack,
    unsigned short* __restrict__ offs,      // [SBLK][OROW] exclusive fine-bin offsets
    unsigned short* __restrict__ sorted)    // [SBLK][RSTRIDE] block-private regions
{
    __shared__ unsigned int hist[NBP];
    __shared__ unsigned int cur[NBP];
    __shared__ unsigned int wsum[4];

    const int k = blockIdx.x;
    const int f0 = k * FPB;
    int n = Fn - f0; if (n < 0) n = 0; if (n > FPB) n = FPB;
    const int n4 = n >> 2;

    for (int i = threadIdx.x; i < NBP; i += 256) hist[i] = 0u;
    __syncthreads();

    // pass 1 (4-wide): read vidx/ef/afunc once, emit gpack, histogram fine bins
    for (int j = threadIdx.x; j < n4; j += 256) {
        const int fb = f0 + 4 * j, e = 3 * fb;
        int4 va = *(const int4*)(vidx + e);
        int4 vb = *(const int4*)(vidx + e + 4);
        int4 vc = *(const int4*)(vidx + e + 8);
        float4 ea = *(const float4*)(ef + e);
        float4 eb = *(const float4*)(ef + e + 4);
        float4 ec = *(const float4*)(ef + e + 8);
        float4 a4 = *(const float4*)(afunc + fb);
        int      vv[12] = {va.x, va.y, va.z, va.w, vb.x, vb.y, vb.z, vb.w, vc.x, vc.y, vc.z, vc.w};
        float    ss[12] = {ea.x, ea.y, ea.z, ea.w, eb.x, eb.y, eb.z, eb.w, ec.x, ec.y, ec.z, ec.w};
        float    aa[4]  = {a4.x, a4.y, a4.z, a4.w};
        unsigned long long gq[4];
        #pragma unroll
        for (int q = 0; q < 4; ++q) {
            int v0 = vv[3 * q], v1 = vv[3 * q + 1], v2 = vv[3 * q + 2];
            unsigned int s0 = ss[3 * q]     > 0.0f ? 1u : 0u;
            unsigned int s1 = ss[3 * q + 1] > 0.0f ? 1u : 0u;
            unsigned int s2 = ss[3 * q + 2] > 0.0f ? 1u : 0u;
            unsigned int act = aa[q] != 0.0f ? 1u : 0u;
            gq[q] = (unsigned long long)(unsigned int)v0
                  | ((unsigned long long)(unsigned int)v1 << 20)
                  | ((unsigned long long)(unsigned int)v2 << 40)
                  | ((unsigned long long)s0 << 60)
                  | ((unsigned long long)s1 << 61)
                  | ((unsigned long long)s2 << 62)
                  | ((unsigned long long)act << 63);
            if (act) {
                atomicAdd(&hist[v0 >> BIN_BITS], 1u);
                atomicAdd(&hist[v1 >> BIN_BITS], 1u);
                atomicAdd(&hist[v2 >> BIN_BITS], 1u);
            }
        }
        *(ulonglong2*)(gpack + fb)     = make_ulonglong2(gq[0], gq[1]);
        *(ulonglong2*)(gpack + fb + 2) = make_ulonglong2(gq[2], gq[3]);
    }
    // scalar tail (0..3 functions)
    for (int i = 4 * n4 + threadIdx.x; i < n; i += 256) {
        const int f = f0 + i, e0 = 3 * f;
        int v0 = vidx[e0], v1 = vidx[e0 + 1], v2 = vidx[e0 + 2];
        unsigned int s0 = ef[e0]     > 0.0f ? 1u : 0u;
        unsigned int s1 = ef[e0 + 1] > 0.0f ? 1u : 0u;
        unsigned int s2 = ef[e0 + 2] > 0.0f ? 1u : 0u;
        unsigned int act = afunc[f] != 0.0f ? 1u : 0u;
        unsigned long long g = (unsigned long long)(unsigned int)v0
                             | ((unsigned long long)(unsigned int)v1 << 20)
                             | ((unsigned long long)(unsigned int)v2 << 40)
                             | ((unsigned long long)s0 << 60)
                             | ((unsigned long long)s1 << 61)
                             | ((unsigned long long)s2 << 62)
                             | ((unsigned long long)act << 63);
        gpack[f] = g;
        if (act) {
            atomicAdd(&hist[v0 >> BIN_BITS], 1u);
            atomicAdd(&hist[v1 >> BIN_BITS], 1u);
            atomicAdd(&hist[v2 >> BIN_BITS], 1u);
        }
    }
    __syncthreads();

    // shuffle-based exclusive scan over 1024 fine bins (256 threads x 4 bins)
    {
        const int t = threadIdx.x, lane = t & 63, wid = t >> 6;
        unsigned int a0 = hist[4 * t], a1 = hist[4 * t + 1];
        unsigned int a2 = hist[4 * t + 2], a3 = hist[4 * t + 3];
        unsigned int tsum = a0 + a1 + a2 + a3;
        unsigned int x = tsum;
        #pragma unroll
        for (int off = 1; off < 64; off <<= 1) {
            unsigned int y = (unsigned int)__shfl_up((int)x, off);
            if (lane >= off) x += y;
        }
        if (lane == 63) wsum[wid] = x;
        __syncthreads();
        unsigned int wbase = 0;
        for (int w = 0; w < wid; ++w) wbase += wsum[w];
        unsigned int e0x = wbase + x - tsum;      // exclusive prefix of bin 4t
        unsigned int e1x = e0x + a0, e2x = e1x + a1, e3x = e2x + a2;
        cur[4 * t] = e0x; cur[4 * t + 1] = e1x; cur[4 * t + 2] = e2x; cur[4 * t + 3] = e3x;
        unsigned short* row = offs + (size_t)k * OROW;
        if (4 * t     <= NB) row[4 * t]     = (unsigned short)e0x;
        if (4 * t + 1 <= NB) row[4 * t + 1] = (unsigned short)e1x;
        if (4 * t + 2 <= NB) row[4 * t + 2] = (unsigned short)e2x;
        if (4 * t + 3 <= NB) row[4 * t + 3] = (unsigned short)e3x;
    }
    __syncthreads();

    // pass 2 (4-wide): re-read gpack (L2-hot) and scatter; entry = 12-bit chunk-local v | sign<<12
    const size_t rbase = (size_t)k * RSTRIDE;
    for (int j = threadIdx.x; j < n4; j += 256) {
        const int fb = f0 + 4 * j;
        ulonglong2 ga = *(const ulonglong2*)(gpack + fb);
        ulonglong2 gb = *(const ulonglong2*)(gpack + fb + 2);
        unsigned long long gq[4] = {ga.x, ga.y, gb.x, gb.y};
        #pragma unroll
        for (int q = 0; q < 4; ++q) {
            unsigned long long g = gq[q];
            if ((long long)g < 0) {
                unsigned int v0 = (unsigned int)(g & 0xFFFFFu);
                unsigned int v1 = (unsigned int)((g >> 20) & 0xFFFFFu);
                unsigned int v2 = (unsigned int)((g >> 40) & 0xFFFFFu);
                unsigned int sl0 = atomicAdd(&cur[v0 >> BIN_BITS], 1u);
                sorted[rbase + sl0] = (unsigned short)((v0 & (CH_SIZE - 1)) | ((unsigned int)((g >> 60) & 1u) << CH_BITS));
                unsigned int sl1 = atomicAdd(&cur[v1 >> BIN_BITS], 1u);
                sorted[rbase + sl1] = (unsigned short)((v1 & (CH_SIZE - 1)) | ((unsigned int)((g >> 61) & 1u) << CH_BITS));
                unsigned int sl2 = atomicAdd(&cur[v2 >> BIN_BITS], 1u);
                sorted[rbase + sl2] = (unsigned short)((v2 & (CH_SIZE - 1)) | ((unsigned int)((g >> 62) & 1u) << CH_BITS));
            }
        }
    }
    for (int i = 4 * n4 + threadIdx.x; i < n; i += 256) {
        unsigned long long g = gpack[f0 + i];
        if ((long long)g < 0) {
            unsigned int v0 = (unsigned int)(g & 0xFFFFFu);
            unsigned int v1 = (unsigned int)((g >> 20) & 0xFFFFFu);
            unsigned int v2 = (unsigned int)((g >> 40) & 0xFFFFFu);
            unsigned int sl0 = atomicAdd(&cur[v0 >> BIN_BITS], 1u);
            sorted[rbase + sl0] = (unsigned short)((v0 & (CH_SIZE - 1)) | ((unsigned int)((g >> 60) & 1u) << CH_BITS));
            unsigned int sl1 = atomicAdd(&cur[v1 >> BIN_BITS], 1u);
            sorted[rbase + sl1] = (unsigned short)((v1 & (CH_SIZE - 1)) | ((unsigned int)((g >> 61) & 1u) << CH_BITS));
            unsigned int sl2 = atomicAdd(&cur[v2 >> BIN_BITS], 1u);
            sorted[rbase + sl2] = (unsigned short)((v2 & (CH_SIZE - 1)) | ((unsigned int)((g >> 62) & 1u) << CH_BITS));
        }
    }
}

// ---- tiled transpose: offs [SBLK][1024] -> offs_T [1024][SBLK] ----
__global__ __launch_bounds__(256) void k_transpose(const unsigned short* __restrict__ in,
                                                   unsigned short* __restrict__ out) {
    __shared__ unsigned short t[64][65];
    const int bx = blockIdx.x;   // 16 col tiles (1024/64)
    const int by = blockIdx.y;   // 32 row tiles (2048/64)
    for (int i = threadIdx.x; i < 64 * 64; i += 256) {
        int r = i >> 6, c = i & 63;
        t[r][c] = in[(size_t)(by * 64 + r) * OROW + (bx * 64 + c)];
    }
    __syncthreads();
    for (int i = threadIdx.x; i < 64 * 64; i += 256) {
        int r = i >> 6, c = i & 63;
        out[(size_t)(bx * 64 + r) * SBLK + (by * 64 + c)] = t[c][r];
    }
}

// ---- per-chunk accumulate + decode. Thread-per-region, contiguous ~49B spans. ----
__global__ __launch_bounds__(1024) void k_accum(
    const unsigned short* __restrict__ offs_T,   // [1024][SBLK]
    const unsigned short* __restrict__ sorted,
    const float* __restrict__ avars,
    unsigned int* __restrict__ packed,
    unsigned long long* __restrict__ avm,
    unsigned long long* __restrict__ svm,
    unsigned char* __restrict__ sgrp)
{
    __shared__ unsigned int acc[CH_SIZE];        // 16 KB
    __shared__ unsigned short row0[SBLK];        // 4 KB
    __shared__ unsigned short row1[SBLK];        // 4 KB
    const int c = blockIdx.x;                    // chunk 0..244
    const int r0 = 4 * c;
    const int r1 = (4 * c + 4 < NB) ? (4 * c + 4) : NB;
    for (int i = threadIdx.x; i < CH_SIZE; i += 1024) acc[i] = 0u;
    for (int i = threadIdx.x; i < SBLK; i += 1024) {
        row0[i] = offs_T[(size_t)r0 * SBLK + i];
        row1[i] = offs_T[(size_t)r1 * SBLK + i];
    }
    __syncthreads();
    for (int k = threadIdx.x; k < SBLK; k += 1024) {   // 2 regions per thread
        const int s0 = row0[k], s1 = row1[k];
        const unsigned short* seg = sorted + (size_t)k * RSTRIDE;
        for (int e = s0; e < s1; ++e) {                // ~25 contiguous u16 loads, independent
            unsigned int p = seg[e];
            atomicAdd(&acc[p & (CH_SIZE - 1)], 0x10000u | (p >> CH_BITS));
        }
    }
    __syncthreads();
    const int vbase = c << CH_BITS;
    for (int i = threadIdx.x; i < CH_SIZE; i += 1024) {
        int v = vbase + i;
        bool valid = v < Vn;
        unsigned int p = valid ? acc[i] : 0u;
        bool av = valid && (avars[v] != 0.0f);
        unsigned int cnt = p >> 16, pos = p & 0xFFFFu;
        bool sv = av && (pos == 0u || pos == cnt);    // deg == |sdeg|
        unsigned long long avb = __ballot(av);
        unsigned long long svb = __ballot(sv);
        if (valid) packed[v] = p;
        if ((threadIdx.x & 63) == 0) {                // word index < AVW (chunk-padded)
            avm[v >> 6] = avb;
            svm[v >> 6] = svb;
            sgrp[v >> 6] = (svb != 0ull) ? 1 : 0;     // group filter byte
        }
    }
}

__global__ void k_zero_tmp(unsigned int* __restrict__ tmp, unsigned char* __restrict__ tgrp) {
    int v = blockIdx.x * blockDim.x + threadIdx.x;
    if (v < Vn) tmp[v] = 0u;
    if (v < AVW) tgrp[v] = 0;
}

// ---- iteration: function side. 2 fns/thread; group filter then fine bitmask. ----
__device__ __forceinline__ void fire_one(unsigned long long g, int f,
                                         unsigned long long* __restrict__ gpack,
                                         const unsigned int* __restrict__ svm32,
                                         const unsigned char* __restrict__ sgrp,
                                         unsigned int* __restrict__ tmp,
                                         unsigned char* __restrict__ tgrp)
{
    if ((long long)g >= 0) return;               // inactive (bit63 clear)
    unsigned int v0 = (unsigned int)(g & 0xFFFFFu);
    unsigned int v1 = (unsigned int)((g >> 20) & 0xFFFFFu);
    unsigned int v2 = (unsigned int)((g >> 40) & 0xFFFFFu);
    // L1-resident group filter (15.7 KB): skip fine L2 probes when no 64-var group has a single
    if (!(sgrp[v0 >> 6] | sgrp[v1 >> 6] | sgrp[v2 >> 6])) return;
    unsigned int hit = ((svm32[v0 >> 5] >> (v0 & 31u)) |
                        (svm32[v1 >> 5] >> (v1 & 31u)) |
                        (svm32[v2 >> 5] >> (v2 & 31u))) & 1u;
    if (!hit) return;
    gpack[f] = g & ~(1ull << 63);                // function deactivates (single_f = 1)
    atomicAdd(&tmp[v0], 0x10000u | (unsigned int)((g >> 60) & 1u));
    atomicAdd(&tmp[v1], 0x10000u | (unsigned int)((g >> 61) & 1u));
    atomicAdd(&tmp[v2], 0x10000u | (unsigned int)((g >> 62) & 1u));
    tgrp[v0 >> 6] = 1; tgrp[v1 >> 6] = 1; tgrp[v2 >> 6] = 1;
}

__global__ void k_funcs(unsigned long long* __restrict__ gpack,
                        const unsigned int* __restrict__ svm32,
                        const unsigned char* __restrict__ sgrp,
                        unsigned int* __restrict__ tmp,
                        unsigned char* __restrict__ tgrp)
{
    int gid = blockIdx.x * blockDim.x + threadIdx.x;
    int f = 2 * gid;
    if (f >= Fn) return;
    ulonglong2 g2 = *(const ulonglong2*)(gpack + f);   // 16B aligned (f even)
    fire_one(g2.x, f,     gpack, svm32, sgrp, tmp, tgrp);
    fire_one(g2.y, f + 1, gpack, svm32, sgrp, tmp, tgrp);
}

// ---- iteration: variable side. packed -= tmp (av-gated, tgrp-skipped); masks refresh.
//      write_deg!=0 on the last iteration: also decode deg to float. ----
__global__ void k_update(unsigned int* __restrict__ packed,
                         unsigned int* __restrict__ tmp,
                         unsigned long long* __restrict__ avm,
                         unsigned long long* __restrict__ svm,
                         unsigned char* __restrict__ sgrp,
                         unsigned char* __restrict__ tgrp,
                         float* __restrict__ deg, int write_deg)
{
    int v = blockIdx.x * blockDim.x + threadIdx.x;
    int lane = threadIdx.x & 63;
    bool valid = v < Vn;
    unsigned long long avw = 0ull, svw = 0ull;
    unsigned char tg = 0;
    if (valid) {
        avw = avm[v >> 6]; svw = svm[v >> 6];          // wave-broadcast loads
        tg = tgrp[v >> 6];                             // wave-uniform dirty-group byte
    }
    bool av_old = valid && ((avw >> lane) & 1ull);
    bool sv     = valid && ((svw >> lane) & 1ull);
    bool av_new = av_old && !sv;                        // av *= (1 - single_v)
    unsigned int p = 0u;
    if (valid) {
        p = packed[v];
        if (tg) {
            unsigned int tp = tmp[v];
            if (tp != 0u) {
                if (av_old) { p -= tp; packed[v] = p; } // deg -= seg*av (field-safe)
                tmp[v] = 0u;
            }
        }
    }
    unsigned int c = p >> 16, pos = p & 0xFFFFu;
    bool nsv = av_new && (pos == 0u || pos == c);       // next single_v
    unsigned long long nsvb = __ballot(nsv);
    if (lane == 0 && valid) {
        svm[v >> 6] = nsvb;
        avm[v >> 6] = avw & ~svw;
        sgrp[v >> 6] = (nsvb != 0ull) ? 1 : 0;
        if (tg) tgrp[v >> 6] = 0;
    }
    if (write_deg && valid) deg[v] = (float)c;
}

extern "C" void kernel_launch(void* const* d_in, const int* in_sizes, int n_in,
                              void* d_out, int out_size, void* d_ws, size_t ws_size,
                              hipStream_t stream) {
    const int*   graph_map        = (const int*)d_in[0];   // row0 = vidx
    const float* edge_feature     = (const float*)d_in[1];
    const float* active_variables = (const float*)d_in[2];
    const float* active_functions = (const float*)d_in[3];
    const int* vidx = graph_map;

    float* deg = (float*)d_out;
    char* ws = (char*)d_ws;
    size_t off = 0;
    unsigned long long* gpack = (unsigned long long*)(ws + off); off += 8ull * Fn;             // 33.6 MB
    unsigned int* packed      = (unsigned int*)(ws + off);       off += 4ull * Vn;             // 4.0 MB
    unsigned long long* avm   = (unsigned long long*)(ws + off); off += 8ull * AVW;            // 125 KB
    unsigned long long* svm   = (unsigned long long*)(ws + off); off += 8ull * AVW;            // 125 KB
    unsigned char* sgrp       = (unsigned char*)(ws + off);      off += (size_t)((AVW + 255) & ~255); // 15.7 KB
    unsigned char* tgrp       = (unsigned char*)(ws + off);      off += (size_t)((AVW + 255) & ~255); // 15.7 KB
    unsigned short* offs      = (unsigned short*)(ws + off);     off += 2ull * SBLK * OROW;    // 4.2 MB
    unsigned short* offs_T    = (unsigned short*)(ws + off);     off += 2ull * SBLK * OROW;    // 4.2 MB
    unsigned short* sorted    = (unsigned short*)(ws + off);     off += 2ull * SBLK * RSTRIDE; // 25.4 MB
    unsigned int* tmp = (unsigned int*)sorted;   // alias: tmp (4 MB) reuses sorted after k_accum
    // total ~71.8 MB

    const int BS = 256;
    const int gV = (Vn + BS - 1) / BS;
    const int gF2 = (Fn / 2 + BS - 1) / BS;

    k_pack_sort<<<SBLK, 256, 0, stream>>>(vidx, edge_feature, active_functions, gpack, offs, sorted);
    k_transpose<<<dim3(OROW / 64, SBLK / 64), 256, 0, stream>>>(offs, offs_T);
    k_accum<<<NCH, 1024, 0, stream>>>(offs_T, sorted, active_variables, packed, avm, svm, sgrp);
    k_zero_tmp<<<gV, BS, 0, stream>>>(tmp, tgrp);
    for (int t = 0; t < Tn; ++t) {
        k_funcs<<<gF2, BS, 0, stream>>>(gpack, (const unsigned int*)svm, sgrp, tmp, tgrp);
        k_update<<<gV, BS, 0, stream>>>(packed, tmp, avm, svm, sgrp, tgrp, deg, (t == Tn - 1) ? 1 : 0);
    }
}